// Round 14
// baseline (163.711 us; speedup 1.0000x reference)
//
#include <hip/hip_runtime.h>
#include <hip/hip_bf16.h>

#define NB 4
#define CCH 256
#define CRD 32
#define NN 4096

typedef __attribute__((ext_vector_type(8))) short short8;
typedef __attribute__((ext_vector_type(4))) float floatx4;
typedef __attribute__((ext_vector_type(4))) int intx4;
typedef __attribute__((ext_vector_type(2))) unsigned int uintx2;

__device__ __forceinline__ unsigned short f2bf(float f) {
  unsigned u = __builtin_bit_cast(unsigned, f);
  u += 0x7FFFu + ((u >> 16) & 1u);
  return (unsigned short)(u >> 16);
}

// Clamped convert: finite bf16 regardless of input (NaN -> -1e4 via IEEE
// maxNum/minNum, +-inf -> +-1e4). Legit qkv values |v| < ~20: transparent.
__device__ __forceinline__ unsigned short f2bf_c(float f) {
  f = fminf(fmaxf(f, -1.0e4f), 1.0e4f);
  unsigned u = __builtin_bit_cast(unsigned, f);
  u += 0x7FFFu + ((u >> 16) & 1u);
  return (unsigned short)(u >> 16);
}

__device__ __forceinline__ unsigned pack2c(float a, float b) {
  return (unsigned)f2bf_c(a) | ((unsigned)f2bf_c(b) << 16);
}

// Output sanitizer: NaN -> -1e30 (IEEE maxNum), +-inf -> +-1e30.
__device__ __forceinline__ float sat(float v) {
  return fminf(fmaxf(v, -1.0e30f), 1.0e30f);
}

__device__ __forceinline__ short8 ld_frag_g(const unsigned short* p) {
  return __builtin_bit_cast(short8, *(const intx4*)p);
}

// ---------------------------------------------------------------------------
// Kernel 1: fused transpose + QKV GEMM -- round-12 version verbatim (the
// 159.1 us best-total configuration; r13's m-merge was neutral, reverted).
// ---------------------------------------------------------------------------
__global__ __launch_bounds__(256) void gemm_qkv_fused(
    const float* __restrict__ x,
    const float* __restrict__ Wq, const float* __restrict__ bq,
    const float* __restrict__ Wk, const float* __restrict__ bk,
    const float* __restrict__ Wv, const float* __restrict__ bv,
    unsigned short* __restrict__ qT, unsigned short* __restrict__ kT,
    unsigned short* __restrict__ vv)
{
  __shared__ __align__(16) unsigned short xs[64 * 264];
  __shared__ __align__(16) unsigned short ws[64 * 264];

  const int tid  = threadIdx.x;
  const int wave = tid >> 6;
  const int lane = tid & 63;
  const int lq   = lane >> 4;
  const int lm   = lane & 15;
  const int n0   = blockIdx.x << 6;
  const int mg   = blockIdx.y;
  const int b    = blockIdx.z;

  {
    const int nn = lane;
    const int cg = wave;
    const float* xb = x + ((size_t)b << 20) + n0 + nn;
#pragma unroll
    for (int it = 0; it < 16; ++it) {
      const int c0 = it * 16 + cg * 4;
      const float v0 = xb[(size_t)(c0 + 0) << 12];
      const float v1 = xb[(size_t)(c0 + 1) << 12];
      const float v2 = xb[(size_t)(c0 + 2) << 12];
      const float v3 = xb[(size_t)(c0 + 3) << 12];
      uintx2 u;
      u[0] = pack2c(v0, v1);
      u[1] = pack2c(v2, v3);
      *(uintx2*)(xs + nn * 264 + c0) = u;
    }
  }

  const int mt_lo = mg ? 3 : 0;
  const int mt_hi = mg ? 5 : 3;

  for (int mt = mt_lo; mt < mt_hi; ++mt) {
#pragma unroll
    for (int i = 0; i < 16; ++i) {
      const int u  = i * 256 + tid;
      const int m  = u >> 6;
      const int o4 = (u & 63) * 4;
      const float* src = (mt == 0)
          ? (m < 32 ? Wq + (size_t)m * CCH : Wk + (size_t)(m - 32) * CCH)
          : Wv + (size_t)((mt - 1) * 64 + m) * CCH;
      const floatx4 f = *(const floatx4*)(src + o4);
      uintx2 uu;
      uu[0] = pack2c(f[0], f[1]);
      uu[1] = pack2c(f[2], f[3]);
      *(uintx2*)(ws + m * 264 + o4) = uu;
    }
    __syncthreads();

    floatx4 acc[4];
#pragma unroll
    for (int t = 0; t < 4; ++t) acc[t] = (floatx4){0.f, 0.f, 0.f, 0.f};

#pragma unroll
    for (int k0 = 0; k0 < 8; ++k0) {
      short8 af[4];
#pragma unroll
      for (int ms = 0; ms < 4; ++ms)
        af[ms] = __builtin_bit_cast(short8,
            *(const intx4*)(ws + (ms * 16 + lm) * 264 + k0 * 32 + lq * 8));
      const short8 bf = __builtin_bit_cast(short8,
          *(const intx4*)(xs + (wave * 16 + lm) * 264 + k0 * 32 + lq * 8));
#pragma unroll
      for (int ms = 0; ms < 4; ++ms)
        acc[ms] = __builtin_amdgcn_mfma_f32_16x16x32_bf16(af[ms], bf,
                                                          acc[ms], 0, 0, 0);
    }
    __syncthreads();

    if (mt == 0) {
      const int n = n0 + wave * 16 + lm;
#pragma unroll
      for (int ms = 0; ms < 4; ++ms) {
        const int d0 = (ms & 1) * 16 + lq * 4;
        const float* bias = (ms < 2) ? bq : bk;
        unsigned short* dst = (ms < 2) ? qT : kT;
        uintx2 u;
        u[0] = pack2c(acc[ms][0] + bias[d0],     acc[ms][1] + bias[d0 + 1]);
        u[1] = pack2c(acc[ms][2] + bias[d0 + 2], acc[ms][3] + bias[d0 + 3]);
        *(uintx2*)(dst + (size_t)(b * NN + n) * CRD + d0) = u;
      }
    } else {
      const int cb = (mt - 1) * 64;
      unsigned short* vb2 = ws;
#pragma unroll
      for (int ms = 0; ms < 4; ++ms)
#pragma unroll
        for (int r = 0; r < 4; ++r) {
          const int c = ms * 16 + lq * 4 + r;
          vb2[c * 64 + wave * 16 + lm] = f2bf_c(acc[ms][r] + bv[cb + c]);
        }
      __syncthreads();
#pragma unroll
      for (int it = 0; it < 2; ++it) {
        const int u = it * 256 + tid;
        const int m = u >> 3;
        const int o = (u & 7) * 8;
        *(intx4*)(vv + (size_t)(b * CCH + cb + m) * NN + n0 + o) =
            *(const intx4*)(vb2 + m * 64 + o);
      }
      __syncthreads();
    }
  }
}

// ---------------------------------------------------------------------------
// Kernel 2: attention, round-14: WINDOW 128 j / 32 ITERATIONS -- the r12
// schedule with half the barrier rounds. Targets the m233-style per-iter
// composite overhead (~1450 cyc fixed per barrier: lgkm drain + arrival
// skew + post-barrier LDS-latency ramp) which r2/r8/r9 proved is not any
// single element. Layout:
//  - V: ring of 4 x 32KB slots, each slot BYTE-IDENTICAL to the old 64-j
//    buffer (c*128 + ((jb^(c&7))*16)). Window k reads slots (2k)&3,(2k+1)&3;
//    stages (2k+2)&3,(2k+3)&3 -- disjoint, race-free under one barrier/iter.
//  - P: 2 parity x 4 wg x [16 rows x 256 B], pad replaced by granule-XOR
//    swizzle (both-sides-same-bijection): store byte = row*256 +
//    ((g^row)<<4) + 2*(lm&7) with g = 2t+(lm>>3); read = single b128 at
//    lm*256 + (((ks*4+lq)^lm)<<4). Element-traced for consistency.
//  LDS = 4*32768 + 2*16384 = 163840 B (exactly the 160 KiB limit).
// ---------------------------------------------------------------------------
__global__ __launch_bounds__(512) void attn_kernel(
    const float* __restrict__ x, const float* __restrict__ gamma_p,
    const unsigned short* __restrict__ qT, const unsigned short* __restrict__ kT,
    const unsigned short* __restrict__ vv, float* __restrict__ out)
{
  __shared__ __align__(16) unsigned char smem[163840];
  const int PB = 131072;   // P region base

  const int tid  = threadIdx.x;
  const int wave = tid >> 6;
  const int wg   = wave >> 1;   // row-group 0..3 (16 i rows each)
  const int cs   = wave & 1;    // j-half of each window (4 of 8 tiles)
  const int lane = tid & 63;
  const int lq   = lane >> 4;
  const int lm   = lane & 15;
  const int xcd = blockIdx.x & 7;
  const int pos = blockIdx.x >> 3;
  const int b   = xcd >> 1;
  const int i0  = (((xcd & 1) << 5) | pos) << 6;

  const unsigned short* kTb = kT + (size_t)b * NN * CRD;
  const unsigned short* vb  = vv + (size_t)b * CCH * NN;

  const short8 qf =
      ld_frag_g(qT + (size_t)(b * NN + i0 + wg * 16 + lm) * CRD + lq * 8);

  // per-lane V-stage coords (per 64-j sub-window; identical to r12)
  int vs_g[4];
  int vs_off[4];
#pragma unroll
  for (int m = 0; m < 4; ++m) {
    const int u  = m * 512 + tid;
    const int c  = u >> 3;
    const int jb = u & 7;
    vs_g[m]   = c * NN + jb * 8;
    vs_off[m] = c * 128 + ((jb ^ (c & 7)) * 16);
  }

  floatx4 acc[8];
#pragma unroll
  for (int t = 0; t < 8; ++t) acc[t] = (floatx4){0.f, 0.f, 0.f, 0.f};
  float lsum[4] = {0.f, 0.f, 0.f, 0.f};

  const floatx4 zf = {0.f, 0.f, 0.f, 0.f};

  // ---- prologue ----
  // window 0 (j 0..127) -> slots 0,1 ; then vreg <- window 1
  intx4 vreg[2][4];
#pragma unroll
  for (int h = 0; h < 2; ++h)
#pragma unroll
    for (int m = 0; m < 4; ++m)
      vreg[h][m] = *(const intx4*)(vb + vs_g[m] + h * 64);
#pragma unroll
  for (int h = 0; h < 2; ++h)
#pragma unroll
    for (int m = 0; m < 4; ++m)
      *(intx4*)(smem + h * 32768 + vs_off[m]) = vreg[h][m];

  // kf <- window 0 (this wave's 4 j-tiles: t = cs*4+jt)
  short8 kf[4];
#pragma unroll
  for (int jt = 0; jt < 4; ++jt)
    kf[jt] = ld_frag_g(kTb + (size_t)((cs * 4 + jt) * 16 + lm) * CRD + lq * 8);

  // P(0) -> parity 0
  {
    unsigned char* pb0 = smem + PB + wg * 4096;
#pragma unroll
    for (int jt = 0; jt < 4; ++jt) {
      const floatx4 S = __builtin_amdgcn_mfma_f32_16x16x32_bf16(
          qf, kf[jt], zf, 0, 0, 0);
      const int t = cs * 4 + jt;
      const int g = 2 * t + (lm >> 3);
#pragma unroll
      for (int r = 0; r < 4; ++r) {
        const float p = __expf(fminf(fmaxf(S[r], -40.f), 40.f));
        lsum[r] += p;
        const int row = lq * 4 + r;
        *(unsigned short*)(pb0 + row * 256 + ((g ^ row) << 4) +
                           2 * (lm & 7)) = f2bf(p);
      }
    }
  }
  // vreg <- window 1; kf <- window 1
#pragma unroll
  for (int h = 0; h < 2; ++h)
#pragma unroll
    for (int m = 0; m < 4; ++m)
      vreg[h][m] = *(const intx4*)(vb + vs_g[m] + 128 + h * 64);
#pragma unroll
  for (int jt = 0; jt < 4; ++jt)
    kf[jt] = ld_frag_g(kTb +
                       (size_t)(128 + (cs * 4 + jt) * 16 + lm) * CRD + lq * 8);

  // ---- main loop: k = 0..30, ONE lgkm-barrier per 128-j window ----
#pragma unroll 1
  for (int k = 0; k < 31; ++k) {
    asm volatile("s_waitcnt lgkmcnt(0)" ::: "memory");
    __builtin_amdgcn_s_barrier();

    unsigned char* pbp = smem + PB + (k & 1) * 16384 + wg * 4096;
    unsigned char* pbn = smem + PB + ((k + 1) & 1) * 16384 + wg * 4096;
    unsigned char* vr0 = smem + (((2 * k)     & 3) << 15);
    unsigned char* vr1 = smem + (((2 * k + 1) & 3) << 15);

    // stage V(k+1) (vreg prefetched last iter) into slots (2k+2),(2k+3) mod 4
#pragma unroll
    for (int h = 0; h < 2; ++h) {
      unsigned char* vw = smem + (((2 * k + 2 + h) & 3) << 15);
#pragma unroll
      for (int m = 0; m < 4; ++m)
        *(intx4*)(vw + vs_off[m]) = vreg[h][m];
    }

    // QK(k+1) + exp + P-store(k+1) -> parity k+1
#pragma unroll
    for (int jt = 0; jt < 4; ++jt) {
      const floatx4 S = __builtin_amdgcn_mfma_f32_16x16x32_bf16(
          qf, kf[jt], zf, 0, 0, 0);
      const int t = cs * 4 + jt;
      const int g = 2 * t + (lm >> 3);
#pragma unroll
      for (int r = 0; r < 4; ++r) {
        const float p = __expf(fminf(fmaxf(S[r], -40.f), 40.f));
        lsum[r] += p;
        const int row = lq * 4 + r;
        *(unsigned short*)(pbn + row * 256 + ((g ^ row) << 4) +
                           2 * (lm & 7)) = f2bf(p);
      }
    }

    // prefetch window k+2 (clamped; redundant at k=30, branch-free body)
    {
      const int w2 = (k + 2 < 32) ? (k + 2) : 31;
      const int j2 = w2 << 7;
#pragma unroll
      for (int h = 0; h < 2; ++h)
#pragma unroll
        for (int m = 0; m < 4; ++m)
          vreg[h][m] = *(const intx4*)(vb + vs_g[m] + j2 + h * 64);
#pragma unroll
      for (int jt = 0; jt < 4; ++jt)
        kf[jt] = ld_frag_g(kTb +
                           (size_t)(j2 + (cs * 4 + jt) * 16 + lm) * CRD + lq * 8);
    }

    // PV(k): 4 K-slices (ks 0,1 from slot 2k; ks 2,3 from slot 2k+1)
#pragma unroll
    for (int ks = 0; ks < 4; ++ks) {
      const unsigned char* vsb = (ks < 2) ? vr0 : vr1;
      const int ksl = ks & 1;
      const short8 pf = __builtin_bit_cast(short8,
          *(const intx4*)(pbp + lm * 256 + (((ks * 4 + lq) ^ lm) << 4)));
#pragma unroll
      for (int nt = 0; nt < 8; ++nt) {
        const int c = cs * 128 + nt * 16 + lm;
        const short8 vf = __builtin_bit_cast(
            short8,
            *(const intx4*)(vsb + c * 128 + (((ksl * 4 + lq) ^ (lm & 7)) * 16)));
        acc[nt] = __builtin_amdgcn_mfma_f32_16x16x32_bf16(pf, vf, acc[nt],
                                                          0, 0, 0);
      }
    }
  }

  // ---- epilogue iteration: PV(31), slots 2,3, parity 1 ----
  asm volatile("s_waitcnt lgkmcnt(0)" ::: "memory");
  __builtin_amdgcn_s_barrier();
  {
    const unsigned char* pbp = smem + PB + 16384 + wg * 4096;
#pragma unroll
    for (int ks = 0; ks < 4; ++ks) {
      const unsigned char* vsb = smem + (((ks < 2) ? 2 : 3) << 15);
      const int ksl = ks & 1;
      const short8 pf = __builtin_bit_cast(short8,
          *(const intx4*)(pbp + lm * 256 + (((ks * 4 + lq) ^ lm) << 4)));
#pragma unroll
      for (int nt = 0; nt < 8; ++nt) {
        const int c = cs * 128 + nt * 16 + lm;
        const short8 vf = __builtin_bit_cast(
            short8,
            *(const intx4*)(vsb + c * 128 + (((ksl * 4 + lq) ^ (lm & 7)) * 16)));
        acc[nt] = __builtin_amdgcn_mfma_f32_16x16x32_bf16(pf, vf, acc[nt],
                                                          0, 0, 0);
      }
    }
  }

  // ---- lsum combine across the cs wave pair ----
  __syncthreads();
  floatx4 lv;
#pragma unroll
  for (int r = 0; r < 4; ++r) lv[r] = lsum[r];
  *(floatx4*)(smem + ((wave * 64 + lane) << 4)) = lv;
  __syncthreads();
  const floatx4 lpart = *(const floatx4*)(smem + (((wave ^ 1) * 64 + lane) << 4));

  float inv[4];
#pragma unroll
  for (int r = 0; r < 4; ++r) {
    float v = lsum[r] + lpart[r];
    v += __shfl_xor(v, 1);
    v += __shfl_xor(v, 2);
    v += __shfl_xor(v, 4);
    v += __shfl_xor(v, 8);
    inv[r] = 1.0f / v;
  }

  // ---- coalesced epilogue via olds[256 c][68 i] fp32 overlay (r12) ----
  __syncthreads();
  float* olds = (float*)smem;
  {
    const int ib = wg * 16 + lq * 4;
#pragma unroll
    for (int nt = 0; nt < 8; ++nt) {
      const int c = cs * 128 + nt * 16 + lm;
      floatx4 o;
#pragma unroll
      for (int r = 0; r < 4; ++r) o[r] = sat(acc[nt][r] * inv[r]);
      *(floatx4*)(olds + c * 68 + ib) = o;
    }
  }
  __syncthreads();

  const float gm = gamma_p[0];
#pragma unroll
  for (int pass = 0; pass < 8; ++pass) {
    const int c  = pass * 32 + (tid >> 4);
    const int i4 = (tid & 15) * 4;
    const floatx4 ov = *(const floatx4*)(olds + c * 68 + i4);
    const size_t idx = (size_t)(b * CCH + c) * NN + i0 + i4;
    const floatx4 xv = *(const floatx4*)(x + idx);
    floatx4 o;
#pragma unroll
    for (int e = 0; e < 4; ++e)
      o[e] = gm * ov[e] + xv[e];
    *(floatx4*)(out + idx) = o;
  }
}

extern "C" void kernel_launch(void* const* d_in, const int* in_sizes, int n_in,
                              void* d_out, int out_size, void* d_ws, size_t ws_size,
                              hipStream_t stream) {
  (void)in_sizes; (void)n_in; (void)out_size; (void)ws_size;
  const float* x     = (const float*)d_in[0];
  const float* Wq    = (const float*)d_in[1];
  const float* bq    = (const float*)d_in[2];
  const float* Wk    = (const float*)d_in[3];
  const float* bk    = (const float*)d_in[4];
  const float* Wv    = (const float*)d_in[5];
  const float* bv    = (const float*)d_in[6];
  const float* gamma = (const float*)d_in[7];

  unsigned short* qT = (unsigned short*)d_ws;              // 1 MiB
  unsigned short* kT = qT + (size_t)NB * NN * CRD;         // 1 MiB
  unsigned short* vv = kT + (size_t)NB * NN * CRD;         // 8 MiB

  gemm_qkv_fused<<<dim3(64, 2, 4), 256, 0, stream>>>(x, Wq, bq, Wk, bk, Wv, bv,
                                                     qT, kT, vv);
  attn_kernel<<<dim3(256, 1, 1), 512, 0, stream>>>(x, gamma, qT, kT, vv,
                                                   (float*)d_out);
}

// Round 15
// 156.684 us; speedup vs baseline: 1.0449x; 1.0449x over previous
//
#include <hip/hip_runtime.h>
#include <hip/hip_bf16.h>

#define NB 4
#define CCH 256
#define CRD 32
#define NN 4096

typedef __attribute__((ext_vector_type(8))) short short8;
typedef __attribute__((ext_vector_type(4))) float floatx4;
typedef __attribute__((ext_vector_type(4))) int intx4;
typedef __attribute__((ext_vector_type(2))) unsigned int uintx2;

__device__ __forceinline__ unsigned short f2bf(float f) {
  unsigned u = __builtin_bit_cast(unsigned, f);
  u += 0x7FFFu + ((u >> 16) & 1u);
  return (unsigned short)(u >> 16);
}

// Clamped convert: finite bf16 regardless of input (NaN -> -1e4 via IEEE
// maxNum/minNum, +-inf -> +-1e4). Legit qkv values |v| < ~20: transparent.
__device__ __forceinline__ unsigned short f2bf_c(float f) {
  f = fminf(fmaxf(f, -1.0e4f), 1.0e4f);
  unsigned u = __builtin_bit_cast(unsigned, f);
  u += 0x7FFFu + ((u >> 16) & 1u);
  return (unsigned short)(u >> 16);
}

__device__ __forceinline__ unsigned pack2c(float a, float b) {
  return (unsigned)f2bf_c(a) | ((unsigned)f2bf_c(b) << 16);
}

// Output sanitizer: NaN -> -1e30 (IEEE maxNum), +-inf -> +-1e30.
__device__ __forceinline__ float sat(float v) {
  return fminf(fmaxf(v, -1.0e30f), 1.0e30f);
}

__device__ __forceinline__ short8 ld_frag_g(const unsigned short* p) {
  return __builtin_bit_cast(short8, *(const intx4*)p);
}

// ---------------------------------------------------------------------------
// Kernel 1: fused transpose + QKV GEMM -- round-12 version verbatim (the
// 159.1 us best-total configuration).
// ---------------------------------------------------------------------------
__global__ __launch_bounds__(256) void gemm_qkv_fused(
    const float* __restrict__ x,
    const float* __restrict__ Wq, const float* __restrict__ bq,
    const float* __restrict__ Wk, const float* __restrict__ bk,
    const float* __restrict__ Wv, const float* __restrict__ bv,
    unsigned short* __restrict__ qT, unsigned short* __restrict__ kT,
    unsigned short* __restrict__ vv)
{
  __shared__ __align__(16) unsigned short xs[64 * 264];
  __shared__ __align__(16) unsigned short ws[64 * 264];

  const int tid  = threadIdx.x;
  const int wave = tid >> 6;
  const int lane = tid & 63;
  const int lq   = lane >> 4;
  const int lm   = lane & 15;
  const int n0   = blockIdx.x << 6;
  const int mg   = blockIdx.y;
  const int b    = blockIdx.z;

  {
    const int nn = lane;
    const int cg = wave;
    const float* xb = x + ((size_t)b << 20) + n0 + nn;
#pragma unroll
    for (int it = 0; it < 16; ++it) {
      const int c0 = it * 16 + cg * 4;
      const float v0 = xb[(size_t)(c0 + 0) << 12];
      const float v1 = xb[(size_t)(c0 + 1) << 12];
      const float v2 = xb[(size_t)(c0 + 2) << 12];
      const float v3 = xb[(size_t)(c0 + 3) << 12];
      uintx2 u;
      u[0] = pack2c(v0, v1);
      u[1] = pack2c(v2, v3);
      *(uintx2*)(xs + nn * 264 + c0) = u;
    }
  }

  const int mt_lo = mg ? 3 : 0;
  const int mt_hi = mg ? 5 : 3;

  for (int mt = mt_lo; mt < mt_hi; ++mt) {
#pragma unroll
    for (int i = 0; i < 16; ++i) {
      const int u  = i * 256 + tid;
      const int m  = u >> 6;
      const int o4 = (u & 63) * 4;
      const float* src = (mt == 0)
          ? (m < 32 ? Wq + (size_t)m * CCH : Wk + (size_t)(m - 32) * CCH)
          : Wv + (size_t)((mt - 1) * 64 + m) * CCH;
      const floatx4 f = *(const floatx4*)(src + o4);
      uintx2 uu;
      uu[0] = pack2c(f[0], f[1]);
      uu[1] = pack2c(f[2], f[3]);
      *(uintx2*)(ws + m * 264 + o4) = uu;
    }
    __syncthreads();

    floatx4 acc[4];
#pragma unroll
    for (int t = 0; t < 4; ++t) acc[t] = (floatx4){0.f, 0.f, 0.f, 0.f};

#pragma unroll
    for (int k0 = 0; k0 < 8; ++k0) {
      short8 af[4];
#pragma unroll
      for (int ms = 0; ms < 4; ++ms)
        af[ms] = __builtin_bit_cast(short8,
            *(const intx4*)(ws + (ms * 16 + lm) * 264 + k0 * 32 + lq * 8));
      const short8 bf = __builtin_bit_cast(short8,
          *(const intx4*)(xs + (wave * 16 + lm) * 264 + k0 * 32 + lq * 8));
#pragma unroll
      for (int ms = 0; ms < 4; ++ms)
        acc[ms] = __builtin_amdgcn_mfma_f32_16x16x32_bf16(af[ms], bf,
                                                          acc[ms], 0, 0, 0);
    }
    __syncthreads();

    if (mt == 0) {
      const int n = n0 + wave * 16 + lm;
#pragma unroll
      for (int ms = 0; ms < 4; ++ms) {
        const int d0 = (ms & 1) * 16 + lq * 4;
        const float* bias = (ms < 2) ? bq : bk;
        unsigned short* dst = (ms < 2) ? qT : kT;
        uintx2 u;
        u[0] = pack2c(acc[ms][0] + bias[d0],     acc[ms][1] + bias[d0 + 1]);
        u[1] = pack2c(acc[ms][2] + bias[d0 + 2], acc[ms][3] + bias[d0 + 3]);
        *(uintx2*)(dst + (size_t)(b * NN + n) * CRD + d0) = u;
      }
    } else {
      const int cb = (mt - 1) * 64;
      unsigned short* vb2 = ws;
#pragma unroll
      for (int ms = 0; ms < 4; ++ms)
#pragma unroll
        for (int r = 0; r < 4; ++r) {
          const int c = ms * 16 + lq * 4 + r;
          vb2[c * 64 + wave * 16 + lm] = f2bf_c(acc[ms][r] + bv[cb + c]);
        }
      __syncthreads();
#pragma unroll
      for (int it = 0; it < 2; ++it) {
        const int u = it * 256 + tid;
        const int m = u >> 3;
        const int o = (u & 7) * 8;
        *(intx4*)(vv + (size_t)(b * CCH + cb + m) * NN + n0 + o) =
            *(const intx4*)(vb2 + m * 64 + o);
      }
      __syncthreads();
    }
  }
}

// ---------------------------------------------------------------------------
// Kernel 2: attention, round-15: 16 WAVES IN ONE BLOCK (1024 threads) --
// the r12 schedule (64-j window, one lgkm-barrier/iter, same swizzles, same
// parity discipline) with per-wave work halved and waves doubled: wave =
// (wg = wave>>2: 16 i rows) x (cs = wave&3: 64 c AND one 16-j QK tile).
// 4 waves/SIMD with ZERO duplicated work (unlike r3/r6/r11 multi-block
// TLP, which duplicated V-staging or QK/exp): per-CU QK, exp, V-stage,
// V-read, P-write totals identical to r12; only P-reads double (+10% LDS).
// Targets the measured non-overlap of LDS(43%)+VALU(29%)+MFMA(7%) pipes
// at 2 waves/SIMD. acc = 4 frags = 16 VGPR.
// ---------------------------------------------------------------------------
__global__ __launch_bounds__(1024) void attn_kernel(
    const float* __restrict__ x, const float* __restrict__ gamma_p,
    const unsigned short* __restrict__ qT, const unsigned short* __restrict__ kT,
    const unsigned short* __restrict__ vv, float* __restrict__ out)
{
  // [0,65536): V double buffer (2 x 256c x 64j bf16, swizzled)
  // [65536, +17408): P double buffer (2 parity x 4 wg x 16 i x 68col shorts)
  __shared__ __align__(16) unsigned char smem[65536 + 2 * 4 * 2176];

  const int tid  = threadIdx.x;
  const int wave = tid >> 6;
  const int wg   = wave >> 2;   // i-group 0..3 (16 rows each)
  const int cs   = wave & 3;    // c-quarter (64 c) AND QK j-tile 0..3
  const int lane = tid & 63;
  const int lq   = lane >> 4;
  const int lm   = lane & 15;
  const int xcd = blockIdx.x & 7;
  const int pos = blockIdx.x >> 3;
  const int b   = xcd >> 1;
  const int i0  = (((xcd & 1) << 5) | pos) << 6;

  const unsigned short* kTb = kT + (size_t)b * NN * CRD;
  const unsigned short* vb  = vv + (size_t)b * CCH * NN;

  const short8 qf =
      ld_frag_g(qT + (size_t)(b * NN + i0 + wg * 16 + lm) * CRD + lq * 8);

  // per-lane V-stage coords: 2048 16B units over [256 c][8 jb]; 2/thread
  int vs_g[2];
  int vs_off[2];
#pragma unroll
  for (int m = 0; m < 2; ++m) {
    const int u  = m * 1024 + tid;
    const int c  = u >> 3;
    const int jb = u & 7;
    vs_g[m]   = c * NN + jb * 8;
    vs_off[m] = c * 128 + ((jb ^ (c & 7)) * 16);
  }

  floatx4 acc[4];
#pragma unroll
  for (int t = 0; t < 4; ++t) acc[t] = (floatx4){0.f, 0.f, 0.f, 0.f};
  float lsum[4] = {0.f, 0.f, 0.f, 0.f};

  const floatx4 zf = {0.f, 0.f, 0.f, 0.f};

  // ---- prologue: build window 0 in parity 0, then prefetch window 1 ----
  intx4 vreg[2];
#pragma unroll
  for (int m = 0; m < 2; ++m)
    vreg[m] = *(const intx4*)(vb + vs_g[m]);
  short8 kf = ld_frag_g(kTb + (size_t)(cs * 16 + lm) * CRD + lq * 8);

#pragma unroll
  for (int m = 0; m < 2; ++m)
    *(intx4*)(smem + vs_off[m]) = vreg[m];
  {
    unsigned char* pb0 = smem + 65536 + wg * 2176;
    const floatx4 S = __builtin_amdgcn_mfma_f32_16x16x32_bf16(
        qf, kf, zf, 0, 0, 0);
#pragma unroll
    for (int r = 0; r < 4; ++r) {
      const float p = __expf(fminf(fmaxf(S[r], -40.f), 40.f));
      lsum[r] += p;
      *(unsigned short*)(pb0 + (lq * 4 + r) * 136 +
                         ((cs * 16 + lm) << 1)) = f2bf(p);
    }
  }
#pragma unroll
  for (int m = 0; m < 2; ++m)
    vreg[m] = *(const intx4*)(vb + vs_g[m] + 64);
  kf = ld_frag_g(kTb + (size_t)(64 + cs * 16 + lm) * CRD + lq * 8);

  // ---- main loop: k = 0..62, one lgkm-barrier per iter, straight-line ----
#pragma unroll 1
  for (int k = 0; k < 63; ++k) {
    asm volatile("s_waitcnt lgkmcnt(0)" ::: "memory");
    __builtin_amdgcn_s_barrier();

    unsigned char* vbp = smem + ((k & 1) << 15);
    unsigned char* pbp = smem + 65536 + (k & 1) * 8704 + wg * 2176;
    unsigned char* vbn = smem + (((k + 1) & 1) << 15);
    unsigned char* pbn = smem + 65536 + ((k + 1) & 1) * 8704 + wg * 2176;

    // stage V(k+1) into parity k+1 (vreg prefetched last iter)
#pragma unroll
    for (int m = 0; m < 2; ++m)
      *(intx4*)(vbn + vs_off[m]) = vreg[m];

    // QK(k+1) + exp + P-store(k+1) -> parity k+1 (this wave's one j-tile)
    {
      const floatx4 S = __builtin_amdgcn_mfma_f32_16x16x32_bf16(
          qf, kf, zf, 0, 0, 0);
#pragma unroll
      for (int r = 0; r < 4; ++r) {
        const float p = __expf(fminf(fmaxf(S[r], -40.f), 40.f));
        lsum[r] += p;
        *(unsigned short*)(pbn + (lq * 4 + r) * 136 +
                           ((cs * 16 + lm) << 1)) = f2bf(p);
      }
    }

    // prefetch window k+2 (clamped; redundant at k=62, branch-free body)
    {
      const int j2 = ((k + 2 < 64) ? (k + 2) : 63) << 6;
#pragma unroll
      for (int m = 0; m < 2; ++m)
        vreg[m] = *(const intx4*)(vb + vs_g[m] + j2);
      kf = ld_frag_g(kTb + (size_t)(j2 + cs * 16 + lm) * CRD + lq * 8);
    }

    // PV(k): this wave's 64-c quarter; reads V/P parity k
#pragma unroll
    for (int ks = 0; ks < 2; ++ks) {
      const unsigned char* pa = pbp + lm * 136 + ks * 64 + lq * 16;
      struct U128 { unsigned long long a, b; } pp;
      pp.a = *(const unsigned long long*)pa;
      pp.b = *(const unsigned long long*)(pa + 8);
      const short8 pf = __builtin_bit_cast(short8, pp);
#pragma unroll
      for (int nt = 0; nt < 4; ++nt) {
        const int c = cs * 64 + nt * 16 + lm;
        const short8 vf = __builtin_bit_cast(
            short8,
            *(const intx4*)(vbp + c * 128 + (((ks * 4 + lq) ^ (lm & 7)) * 16)));
        acc[nt] = __builtin_amdgcn_mfma_f32_16x16x32_bf16(pf, vf, acc[nt],
                                                          0, 0, 0);
      }
    }
  }

  // ---- epilogue iteration: PV(63), parity 1 ----
  asm volatile("s_waitcnt lgkmcnt(0)" ::: "memory");
  __builtin_amdgcn_s_barrier();
  {
    const unsigned char* vbp = smem + (1 << 15);
    const unsigned char* pbp = smem + 65536 + 8704 + wg * 2176;
#pragma unroll
    for (int ks = 0; ks < 2; ++ks) {
      const unsigned char* pa = pbp + lm * 136 + ks * 64 + lq * 16;
      struct U128 { unsigned long long a, b; } pp;
      pp.a = *(const unsigned long long*)pa;
      pp.b = *(const unsigned long long*)(pa + 8);
      const short8 pf = __builtin_bit_cast(short8, pp);
#pragma unroll
      for (int nt = 0; nt < 4; ++nt) {
        const int c = cs * 64 + nt * 16 + lm;
        const short8 vf = __builtin_bit_cast(
            short8,
            *(const intx4*)(vbp + c * 128 + (((ks * 4 + lq) ^ (lm & 7)) * 16)));
        acc[nt] = __builtin_amdgcn_mfma_f32_16x16x32_bf16(pf, vf, acc[nt],
                                                          0, 0, 0);
      }
    }
  }

  // ---- lsum combine across the 4 cs waves of each wg ----
  // after lm-reduce, every lane of a wave holds the row-sums for its j-tile
#pragma unroll
  for (int r = 0; r < 4; ++r) {
    float v = lsum[r];
    v += __shfl_xor(v, 1);
    v += __shfl_xor(v, 2);
    v += __shfl_xor(v, 4);
    v += __shfl_xor(v, 8);
    lsum[r] = v;
  }
  __syncthreads();   // all PV(63) reads done; smem reusable
  {
    floatx4 lv;
#pragma unroll
    for (int r = 0; r < 4; ++r) lv[r] = lsum[r];
    *(floatx4*)(smem + ((wave * 64 + lane) << 4)) = lv;
  }
  __syncthreads();
  float inv[4];
  {
    floatx4 s = {0.f, 0.f, 0.f, 0.f};
#pragma unroll
    for (int q = 0; q < 4; ++q) {
      const floatx4 lp =
          *(const floatx4*)(smem + (((wg * 4 + q) * 64 + lane) << 4));
      s = s + lp;
    }
#pragma unroll
    for (int r = 0; r < 4; ++r) inv[r] = 1.0f / s[r];
  }

  // ---- coalesced epilogue via olds[256 c][68 i] fp32 overlay ----
  __syncthreads();   // lsum-buffer reads done; smem reusable as olds
  float* olds = (float*)smem;
  {
    const int ib = wg * 16 + lq * 4;
#pragma unroll
    for (int nt = 0; nt < 4; ++nt) {
      const int c = cs * 64 + nt * 16 + lm;
      floatx4 o;
#pragma unroll
      for (int r = 0; r < 4; ++r) o[r] = sat(acc[nt][r] * inv[r]);
      *(floatx4*)(olds + c * 68 + ib) = o;
    }
  }
  __syncthreads();

  const float gm = gamma_p[0];
#pragma unroll
  for (int pass = 0; pass < 4; ++pass) {
    const int c  = pass * 64 + (tid >> 4);
    const int i4 = (tid & 15) * 4;
    const floatx4 ov = *(const floatx4*)(olds + c * 68 + i4);
    const size_t idx = (size_t)(b * CCH + c) * NN + i0 + i4;
    const floatx4 xv = *(const floatx4*)(x + idx);
    floatx4 o;
#pragma unroll
    for (int e = 0; e < 4; ++e)
      o[e] = gm * ov[e] + xv[e];
    *(floatx4*)(out + idx) = o;
  }
}

extern "C" void kernel_launch(void* const* d_in, const int* in_sizes, int n_in,
                              void* d_out, int out_size, void* d_ws, size_t ws_size,
                              hipStream_t stream) {
  (void)in_sizes; (void)n_in; (void)out_size; (void)ws_size;
  const float* x     = (const float*)d_in[0];
  const float* Wq    = (const float*)d_in[1];
  const float* bq    = (const float*)d_in[2];
  const float* Wk    = (const float*)d_in[3];
  const float* bk    = (const float*)d_in[4];
  const float* Wv    = (const float*)d_in[5];
  const float* bv    = (const float*)d_in[6];
  const float* gamma = (const float*)d_in[7];

  unsigned short* qT = (unsigned short*)d_ws;              // 1 MiB
  unsigned short* kT = qT + (size_t)NB * NN * CRD;         // 1 MiB
  unsigned short* vv = kT + (size_t)NB * NN * CRD;         // 8 MiB

  gemm_qkv_fused<<<dim3(64, 2, 4), 256, 0, stream>>>(x, Wq, bq, Wk, bk, Wv, bv,
                                                     qT, kT, vv);
  attn_kernel<<<dim3(256, 1, 1), 1024, 0, stream>>>(x, gamma, qT, kT, vv,
                                                    (float*)d_out);
}

// Round 16
// 150.359 us; speedup vs baseline: 1.0888x; 1.0421x over previous
//
#include <hip/hip_runtime.h>
#include <hip/hip_bf16.h>

#define NB 4
#define CCH 256
#define CRD 32
#define NN 4096

typedef __attribute__((ext_vector_type(8))) short short8;
typedef __attribute__((ext_vector_type(4))) float floatx4;
typedef __attribute__((ext_vector_type(4))) int intx4;
typedef __attribute__((ext_vector_type(2))) unsigned int uintx2;

__device__ __forceinline__ unsigned short f2bf(float f) {
  unsigned u = __builtin_bit_cast(unsigned, f);
  u += 0x7FFFu + ((u >> 16) & 1u);
  return (unsigned short)(u >> 16);
}

// Clamped convert: finite bf16 regardless of input (NaN -> -1e4 via IEEE
// maxNum/minNum, +-inf -> +-1e4). Legit qkv values |v| < ~20: transparent.
__device__ __forceinline__ unsigned short f2bf_c(float f) {
  f = fminf(fmaxf(f, -1.0e4f), 1.0e4f);
  unsigned u = __builtin_bit_cast(unsigned, f);
  u += 0x7FFFu + ((u >> 16) & 1u);
  return (unsigned short)(u >> 16);
}

__device__ __forceinline__ unsigned pack2c(float a, float b) {
  return (unsigned)f2bf_c(a) | ((unsigned)f2bf_c(b) << 16);
}

// Output sanitizer: NaN -> -1e30 (IEEE maxNum), +-inf -> +-1e30.
__device__ __forceinline__ float sat(float v) {
  return fminf(fmaxf(v, -1.0e30f), 1.0e30f);
}

__device__ __forceinline__ short8 ld_frag_g(const unsigned short* p) {
  return __builtin_bit_cast(short8, *(const intx4*)p);
}

// ---------------------------------------------------------------------------
// Kernel 1: fused transpose + QKV GEMM -- round-12 version verbatim (the
// best-total configuration).
// ---------------------------------------------------------------------------
__global__ __launch_bounds__(256) void gemm_qkv_fused(
    const float* __restrict__ x,
    const float* __restrict__ Wq, const float* __restrict__ bq,
    const float* __restrict__ Wk, const float* __restrict__ bk,
    const float* __restrict__ Wv, const float* __restrict__ bv,
    unsigned short* __restrict__ qT, unsigned short* __restrict__ kT,
    unsigned short* __restrict__ vv)
{
  __shared__ __align__(16) unsigned short xs[64 * 264];
  __shared__ __align__(16) unsigned short ws[64 * 264];

  const int tid  = threadIdx.x;
  const int wave = tid >> 6;
  const int lane = tid & 63;
  const int lq   = lane >> 4;
  const int lm   = lane & 15;
  const int n0   = blockIdx.x << 6;
  const int mg   = blockIdx.y;
  const int b    = blockIdx.z;

  {
    const int nn = lane;
    const int cg = wave;
    const float* xb = x + ((size_t)b << 20) + n0 + nn;
#pragma unroll
    for (int it = 0; it < 16; ++it) {
      const int c0 = it * 16 + cg * 4;
      const float v0 = xb[(size_t)(c0 + 0) << 12];
      const float v1 = xb[(size_t)(c0 + 1) << 12];
      const float v2 = xb[(size_t)(c0 + 2) << 12];
      const float v3 = xb[(size_t)(c0 + 3) << 12];
      uintx2 u;
      u[0] = pack2c(v0, v1);
      u[1] = pack2c(v2, v3);
      *(uintx2*)(xs + nn * 264 + c0) = u;
    }
  }

  const int mt_lo = mg ? 3 : 0;
  const int mt_hi = mg ? 5 : 3;

  for (int mt = mt_lo; mt < mt_hi; ++mt) {
#pragma unroll
    for (int i = 0; i < 16; ++i) {
      const int u  = i * 256 + tid;
      const int m  = u >> 6;
      const int o4 = (u & 63) * 4;
      const float* src = (mt == 0)
          ? (m < 32 ? Wq + (size_t)m * CCH : Wk + (size_t)(m - 32) * CCH)
          : Wv + (size_t)((mt - 1) * 64 + m) * CCH;
      const floatx4 f = *(const floatx4*)(src + o4);
      uintx2 uu;
      uu[0] = pack2c(f[0], f[1]);
      uu[1] = pack2c(f[2], f[3]);
      *(uintx2*)(ws + m * 264 + o4) = uu;
    }
    __syncthreads();

    floatx4 acc[4];
#pragma unroll
    for (int t = 0; t < 4; ++t) acc[t] = (floatx4){0.f, 0.f, 0.f, 0.f};

#pragma unroll
    for (int k0 = 0; k0 < 8; ++k0) {
      short8 af[4];
#pragma unroll
      for (int ms = 0; ms < 4; ++ms)
        af[ms] = __builtin_bit_cast(short8,
            *(const intx4*)(ws + (ms * 16 + lm) * 264 + k0 * 32 + lq * 8));
      const short8 bf = __builtin_bit_cast(short8,
          *(const intx4*)(xs + (wave * 16 + lm) * 264 + k0 * 32 + lq * 8));
#pragma unroll
      for (int ms = 0; ms < 4; ++ms)
        acc[ms] = __builtin_amdgcn_mfma_f32_16x16x32_bf16(af[ms], bf,
                                                          acc[ms], 0, 0, 0);
    }
    __syncthreads();

    if (mt == 0) {
      const int n = n0 + wave * 16 + lm;
#pragma unroll
      for (int ms = 0; ms < 4; ++ms) {
        const int d0 = (ms & 1) * 16 + lq * 4;
        const float* bias = (ms < 2) ? bq : bk;
        unsigned short* dst = (ms < 2) ? qT : kT;
        uintx2 u;
        u[0] = pack2c(acc[ms][0] + bias[d0],     acc[ms][1] + bias[d0 + 1]);
        u[1] = pack2c(acc[ms][2] + bias[d0 + 2], acc[ms][3] + bias[d0 + 3]);
        *(uintx2*)(dst + (size_t)(b * NN + n) * CRD + d0) = u;
      }
    } else {
      const int cb = (mt - 1) * 64;
      unsigned short* vb2 = ws;
#pragma unroll
      for (int ms = 0; ms < 4; ++ms)
#pragma unroll
        for (int r = 0; r < 4; ++r) {
          const int c = ms * 16 + lq * 4 + r;
          vb2[c * 64 + wave * 16 + lm] = f2bf_c(acc[ms][r] + bv[cb + c]);
        }
      __syncthreads();
#pragma unroll
      for (int it = 0; it < 2; ++it) {
        const int u = it * 256 + tid;
        const int m = u >> 3;
        const int o = (u & 7) * 8;
        *(intx4*)(vv + (size_t)(b * CCH + cb + m) * NN + n0 + o) =
            *(const intx4*)(vb2 + m * 64 + o);
      }
      __syncthreads();
    }
  }
}

// ---------------------------------------------------------------------------
// Kernel 2: attention, round-16: J-SPLIT V-REUSE at 16 waves -- the r15
// kernel (74.7 us best; 1024 thr, 4 waves/SIMD) with wave shape changed
// from (wg 4 x cs 4) to (ig 2 x cs 4 x js 2):
//   QK: wave computes i-tile it = 2ig+js, j-tile cs (16 tiles, ZERO dup,
//       same totals as r15).
//   PV: wave covers 32 i (tiles 2ig, 2ig+1) x 64 c (quarter cs) x its js
//       j-half only: each V b128 read feeds TWO P frags -> V-read LDS
//       traffic HALVES (128->64 KB/iter/CU; total LDS 200->136 KB, -32%).
//       This is r2's V-reuse retried in the correct regime (rule #23):
//       r2 was null in the 2-wave/SIMD latency regime; r15 moved us into
//       the LDS-throughput regime where this pipe is the binding one.
//   acc = 8 frags (32 VGPR); j-half partials combined through the olds
//   overlay (scaled-add; inv depends on i only so scale-then-add is exact).
// ---------------------------------------------------------------------------
__global__ __launch_bounds__(1024) void attn_kernel(
    const float* __restrict__ x, const float* __restrict__ gamma_p,
    const unsigned short* __restrict__ qT, const unsigned short* __restrict__ kT,
    const unsigned short* __restrict__ vv, float* __restrict__ out)
{
  // [0,65536): V double buffer (2 x 256c x 64j bf16, swizzled)
  // [65536, +17408): P double buffer (2 parity x 4 i-tiles x 16 x 68col)
  __shared__ __align__(16) unsigned char smem[65536 + 2 * 4 * 2176];

  const int tid  = threadIdx.x;
  const int wave = tid >> 6;
  const int ig   = wave >> 3;        // i-pair 0..1 (32 rows)
  const int cs   = (wave >> 1) & 3;  // c-quarter (64 c) AND QK j-tile
  const int js   = wave & 1;         // PV j-half; also selects QK i-subtile
  const int it   = ig * 2 + js;      // QK i-tile 0..3
  const int lane = tid & 63;
  const int lq   = lane >> 4;
  const int lm   = lane & 15;
  const int xcd = blockIdx.x & 7;
  const int pos = blockIdx.x >> 3;
  const int b   = xcd >> 1;
  const int i0  = (((xcd & 1) << 5) | pos) << 6;

  const unsigned short* kTb = kT + (size_t)b * NN * CRD;
  const unsigned short* vb  = vv + (size_t)b * CCH * NN;

  const short8 qf =
      ld_frag_g(qT + (size_t)(b * NN + i0 + it * 16 + lm) * CRD + lq * 8);

  // per-lane V-stage coords: 2048 16B units over [256 c][8 jb]; 2/thread
  int vs_g[2];
  int vs_off[2];
#pragma unroll
  for (int m = 0; m < 2; ++m) {
    const int u  = m * 1024 + tid;
    const int c  = u >> 3;
    const int jb = u & 7;
    vs_g[m]   = c * NN + jb * 8;
    vs_off[m] = c * 128 + ((jb ^ (c & 7)) * 16);
  }

  floatx4 acc[8];                     // [f*4+nt]: i-tile 2ig+f, c-frag nt
#pragma unroll
  for (int t = 0; t < 8; ++t) acc[t] = (floatx4){0.f, 0.f, 0.f, 0.f};
  float lsum[4] = {0.f, 0.f, 0.f, 0.f};

  const floatx4 zf = {0.f, 0.f, 0.f, 0.f};

  // ---- prologue: build window 0 in parity 0, then prefetch window 1 ----
  intx4 vreg[2];
#pragma unroll
  for (int m = 0; m < 2; ++m)
    vreg[m] = *(const intx4*)(vb + vs_g[m]);
  short8 kf = ld_frag_g(kTb + (size_t)(cs * 16 + lm) * CRD + lq * 8);

#pragma unroll
  for (int m = 0; m < 2; ++m)
    *(intx4*)(smem + vs_off[m]) = vreg[m];
  {
    unsigned char* pb0 = smem + 65536 + it * 2176;
    const floatx4 S = __builtin_amdgcn_mfma_f32_16x16x32_bf16(
        qf, kf, zf, 0, 0, 0);
#pragma unroll
    for (int r = 0; r < 4; ++r) {
      const float p = __expf(fminf(fmaxf(S[r], -40.f), 40.f));
      lsum[r] += p;
      *(unsigned short*)(pb0 + (lq * 4 + r) * 136 +
                         ((cs * 16 + lm) << 1)) = f2bf(p);
    }
  }
#pragma unroll
  for (int m = 0; m < 2; ++m)
    vreg[m] = *(const intx4*)(vb + vs_g[m] + 64);
  kf = ld_frag_g(kTb + (size_t)(64 + cs * 16 + lm) * CRD + lq * 8);

  // ---- main loop: k = 0..62, one lgkm-barrier per iter, straight-line ----
#pragma unroll 1
  for (int k = 0; k < 63; ++k) {
    asm volatile("s_waitcnt lgkmcnt(0)" ::: "memory");
    __builtin_amdgcn_s_barrier();

    unsigned char* vbp = smem + ((k & 1) << 15);
    unsigned char* ppar = smem + 65536 + (k & 1) * 8704;
    unsigned char* vbn = smem + (((k + 1) & 1) << 15);
    unsigned char* pnxt = smem + 65536 + ((k + 1) & 1) * 8704;

    // stage V(k+1) into parity k+1 (vreg prefetched last iter)
#pragma unroll
    for (int m = 0; m < 2; ++m)
      *(intx4*)(vbn + vs_off[m]) = vreg[m];

    // QK(k+1) + exp + P-store(k+1): i-tile it, j-tile cs -> parity k+1
    {
      const floatx4 S = __builtin_amdgcn_mfma_f32_16x16x32_bf16(
          qf, kf, zf, 0, 0, 0);
      unsigned char* pbn = pnxt + it * 2176;
#pragma unroll
      for (int r = 0; r < 4; ++r) {
        const float p = __expf(fminf(fmaxf(S[r], -40.f), 40.f));
        lsum[r] += p;
        *(unsigned short*)(pbn + (lq * 4 + r) * 136 +
                           ((cs * 16 + lm) << 1)) = f2bf(p);
      }
    }

    // prefetch window k+2 (clamped; redundant at k=62, branch-free body)
    {
      const int j2 = ((k + 2 < 64) ? (k + 2) : 63) << 6;
#pragma unroll
      for (int m = 0; m < 2; ++m)
        vreg[m] = *(const intx4*)(vb + vs_g[m] + j2);
      kf = ld_frag_g(kTb + (size_t)(j2 + cs * 16 + lm) * CRD + lq * 8);
    }

    // PV(k): i-tiles 2ig,2ig+1 x c-quarter cs x j-half js; each V read
    // feeds BOTH P frags (the V-reuse)
    {
      short8 pf[2];
#pragma unroll
      for (int f = 0; f < 2; ++f) {
        const unsigned char* pa =
            ppar + (ig * 2 + f) * 2176 + lm * 136 + js * 64 + lq * 16;
        struct U128 { unsigned long long a, b; } pp;
        pp.a = *(const unsigned long long*)pa;
        pp.b = *(const unsigned long long*)(pa + 8);
        pf[f] = __builtin_bit_cast(short8, pp);
      }
#pragma unroll
      for (int nt = 0; nt < 4; ++nt) {
        const int c = cs * 64 + nt * 16 + lm;
        const short8 vf = __builtin_bit_cast(
            short8,
            *(const intx4*)(vbp + c * 128 + (((js * 4 + lq) ^ (lm & 7)) * 16)));
#pragma unroll
        for (int f = 0; f < 2; ++f)
          acc[f * 4 + nt] = __builtin_amdgcn_mfma_f32_16x16x32_bf16(
              pf[f], vf, acc[f * 4 + nt], 0, 0, 0);
      }
    }
  }

  // ---- epilogue iteration: PV(63), parity 1 ----
  asm volatile("s_waitcnt lgkmcnt(0)" ::: "memory");
  __builtin_amdgcn_s_barrier();
  {
    const unsigned char* vbp = smem + (1 << 15);
    const unsigned char* ppar = smem + 65536 + 8704;
    short8 pf[2];
#pragma unroll
    for (int f = 0; f < 2; ++f) {
      const unsigned char* pa =
          ppar + (ig * 2 + f) * 2176 + lm * 136 + js * 64 + lq * 16;
      struct U128 { unsigned long long a, b; } pp;
      pp.a = *(const unsigned long long*)pa;
      pp.b = *(const unsigned long long*)(pa + 8);
      pf[f] = __builtin_bit_cast(short8, pp);
    }
#pragma unroll
    for (int nt = 0; nt < 4; ++nt) {
      const int c = cs * 64 + nt * 16 + lm;
      const short8 vf = __builtin_bit_cast(
          short8,
          *(const intx4*)(vbp + c * 128 + (((js * 4 + lq) ^ (lm & 7)) * 16)));
#pragma unroll
      for (int f = 0; f < 2; ++f)
        acc[f * 4 + nt] = __builtin_amdgcn_mfma_f32_16x16x32_bf16(
            pf[f], vf, acc[f * 4 + nt], 0, 0, 0);
    }
  }

  // ---- lsum: lm-reduce, publish per (it, cs), combine per i-tile ----
#pragma unroll
  for (int r = 0; r < 4; ++r) {
    float v = lsum[r];
    v += __shfl_xor(v, 1);
    v += __shfl_xor(v, 2);
    v += __shfl_xor(v, 4);
    v += __shfl_xor(v, 8);
    lsum[r] = v;
  }
  __syncthreads();   // all PV(63) reads done; smem reusable
  {
    floatx4 lv;
#pragma unroll
    for (int r = 0; r < 4; ++r) lv[r] = lsum[r];
    *(floatx4*)(smem + (((it * 4 + cs) * 64 + lane) << 4)) = lv;
  }
  __syncthreads();
  floatx4 invf[2];
#pragma unroll
  for (int f = 0; f < 2; ++f) {
    floatx4 s = {0.f, 0.f, 0.f, 0.f};
#pragma unroll
    for (int q = 0; q < 4; ++q) {
      const floatx4 lp = *(const floatx4*)(
          smem + ((((ig * 2 + f) * 4 + q) * 64 + lane) << 4));
      s = s + lp;
    }
#pragma unroll
    for (int r = 0; r < 4; ++r) invf[f][r] = 1.0f / s[r];
  }
  __syncthreads();   // lsum-buffer reads done; smem reusable as olds

  // ---- j-half combine + coalesced epilogue via olds[256 c][68 i] ----
  float* olds = (float*)smem;
  if (js == 0) {
#pragma unroll
    for (int f = 0; f < 2; ++f)
#pragma unroll
      for (int nt = 0; nt < 4; ++nt) {
        const int c  = cs * 64 + nt * 16 + lm;
        const int ib = (ig * 2 + f) * 16 + lq * 4;
        floatx4 o;
#pragma unroll
        for (int r = 0; r < 4; ++r) o[r] = sat(acc[f * 4 + nt][r] * invf[f][r]);
        *(floatx4*)(olds + c * 68 + ib) = o;
      }
  }
  __syncthreads();
  if (js == 1) {
#pragma unroll
    for (int f = 0; f < 2; ++f)
#pragma unroll
      for (int nt = 0; nt < 4; ++nt) {
        const int c  = cs * 64 + nt * 16 + lm;
        const int ib = (ig * 2 + f) * 16 + lq * 4;
        float* dst = olds + c * 68 + ib;
        floatx4 o = *(const floatx4*)dst;
#pragma unroll
        for (int r = 0; r < 4; ++r)
          o[r] += sat(acc[f * 4 + nt][r] * invf[f][r]);
        *(floatx4*)dst = o;
      }
  }
  __syncthreads();

  const float gm = gamma_p[0];
#pragma unroll
  for (int pass = 0; pass < 4; ++pass) {
    const int c  = pass * 64 + (tid >> 4);
    const int i4 = (tid & 15) * 4;
    const floatx4 ov = *(const floatx4*)(olds + c * 68 + i4);
    const size_t idx = (size_t)(b * CCH + c) * NN + i0 + i4;
    const floatx4 xv = *(const floatx4*)(x + idx);
    floatx4 o;
#pragma unroll
    for (int e = 0; e < 4; ++e)
      o[e] = gm * ov[e] + xv[e];
    *(floatx4*)(out + idx) = o;
  }
}

extern "C" void kernel_launch(void* const* d_in, const int* in_sizes, int n_in,
                              void* d_out, int out_size, void* d_ws, size_t ws_size,
                              hipStream_t stream) {
  (void)in_sizes; (void)n_in; (void)out_size; (void)ws_size;
  const float* x     = (const float*)d_in[0];
  const float* Wq    = (const float*)d_in[1];
  const float* bq    = (const float*)d_in[2];
  const float* Wk    = (const float*)d_in[3];
  const float* bk    = (const float*)d_in[4];
  const float* Wv    = (const float*)d_in[5];
  const float* bv    = (const float*)d_in[6];
  const float* gamma = (const float*)d_in[7];

  unsigned short* qT = (unsigned short*)d_ws;              // 1 MiB
  unsigned short* kT = qT + (size_t)NB * NN * CRD;         // 1 MiB
  unsigned short* vv = kT + (size_t)NB * NN * CRD;         // 8 MiB

  gemm_qkv_fused<<<dim3(64, 2, 4), 256, 0, stream>>>(x, Wq, bq, Wk, bk, Wv, bv,
                                                     qT, kT, vv);
  attn_kernel<<<dim3(256, 1, 1), 1024, 0, stream>>>(x, gamma, qT, kT, vv,
                                                    (float*)d_out);
}